// Round 3
// baseline (467.225 us; speedup 1.0000x reference)
//
#include <hip/hip_runtime.h>
#include <hip/hip_bf16.h>

// SynthesisConv: style affine -> demod -> conv_transpose(up=2,k=3) -> FIR 4x4
// -> noise + bias + lrelu*sqrt(2) + clamp(+-256).
// Inputs: float32.  Output: float32 (proven by R1 error signature 267.375 =
// 258+9.375: f32 readback of bf16-pair writes; bf16 readback caps at 265.375).
//
// Decomposition (exact):
//   style folds into x (B-operand column scale), dcoef folds into epilogue.
//   Z[(o,ky,kx),(b,i,j)] = sum_c w[o,c,ky,kx] * x'[b,c,i,j]   (one shared GEMM)
//   y65[2i+ky, 2j+kx] += Z ; out = FIR(y65)*dcoef + noise*ns + bias -> lrelu -> clamp
// Z chunked over 4 batches (ws reuse, stream-serialized): ws = 59.3 MB.

typedef unsigned short u16;
typedef u16 u16x8 __attribute__((ext_vector_type(8)));
typedef __bf16 bf16x8 __attribute__((ext_vector_type(8)));
typedef float f32x4 __attribute__((ext_vector_type(4)));

#define NB 16
#define CHUNK 4

__device__ __forceinline__ float bf2f(u16 v) {
  unsigned int u = ((unsigned int)v) << 16;
  float f;
  __builtin_memcpy(&f, &u, 4);
  return f;
}
__device__ __forceinline__ u16 f2bf(float f) {
  __hip_bfloat16 h = __float2bfloat16(f);  // RNE
  u16 r;
  __builtin_memcpy(&r, &h, 2);
  return r;
}

// ---- style[b,c] = sum_k wl[b,k]*aw[c,k]/sqrt(512) + ab[c] ---------------------
__global__ __launch_bounds__(256) void k_style(const float* __restrict__ wl,
                                               const float* __restrict__ aw,
                                               const float* __restrict__ ab,
                                               float* __restrict__ style) {
  __shared__ float lw[512];
  const int b = blockIdx.y;
  const int c = blockIdx.x * 256 + threadIdx.x;
  for (int k = threadIdx.x; k < 512; k += 256) lw[k] = wl[b * 512 + k];
  __syncthreads();
  const float* row = aw + (size_t)c * 512;
  float acc = 0.f;
#pragma unroll 8
  for (int k = 0; k < 512; ++k) acc += lw[k] * row[k];
  style[b * 512 + c] = acc * 0.04419417382415922f + ab[c];
}

// ---- dcoef[b,o] = rsqrt(sum_c style^2 * sum_k w[o,c,k]^2 + 1e-8) -------------
__global__ __launch_bounds__(256) void k_dcoef(const float* __restrict__ cw,
                                               const float* __restrict__ style,
                                               float* __restrict__ dcoef) {
  __shared__ float wsq[512];
  __shared__ float r4[4];
  const int o = blockIdx.x, t = threadIdx.x;
  for (int c = t; c < 512; c += 256) {
    const float* p = cw + (size_t)(o * 512 + c) * 9;
    float s = 0.f;
#pragma unroll
    for (int k = 0; k < 9; ++k) {
      float v = p[k];
      s += v * v;
    }
    wsq[c] = s;
  }
  __syncthreads();
  for (int b = 0; b < NB; ++b) {
    float part = 0.f;
    for (int c = t; c < 512; c += 256) {
      float st = style[b * 512 + c];
      part += st * st * wsq[c];
    }
#pragma unroll
    for (int off = 32; off; off >>= 1) part += __shfl_down(part, off, 64);
    if ((t & 63) == 0) r4[t >> 6] = part;
    __syncthreads();
    if (t == 0) dcoef[b * 512 + o] = 1.0f / sqrtf(r4[0] + r4[1] + r4[2] + r4[3] + 1e-8f);
    __syncthreads();
  }
}

// ---- pack W2[(o*9+kp)*512 + c] = bf16(cw[(o*512+c)*9 + kp]) ------------------
__global__ __launch_bounds__(256) void k_pack(const float* __restrict__ cw,
                                              u16* __restrict__ W2) {
  int t = blockIdx.x * 256 + threadIdx.x;  // < 4608*512
  int c = t & 511;
  int r = t >> 9;
  int kp = r % 9;
  int o = r / 9;
  W2[t] = f2bf(cw[(size_t)(o * 512 + c) * 9 + kp]);
}

// ---- xT[b,s,c] = bf16(x[b,c,s] * style[b,c])  (LDS 64x64 transpose) ----------
__global__ __launch_bounds__(256) void k_xt(const float* __restrict__ x,
                                            const float* __restrict__ style,
                                            u16* __restrict__ xT) {
  __shared__ u16 tile[64 * 66];
  const int b = blockIdx.z, c0 = blockIdx.y << 6, s0 = blockIdx.x << 6;
  const int t = threadIdx.x;
#pragma unroll
  for (int i = 0; i < 16; ++i) {
    int e = i * 256 + t;
    int cc = e >> 6, ss = e & 63;
    int c = c0 + cc;
    float v = x[(size_t)(b * 512 + c) * 1024 + s0 + ss] * style[b * 512 + c];
    tile[cc * 66 + ss] = f2bf(v);
  }
  __syncthreads();
#pragma unroll
  for (int i = 0; i < 16; ++i) {
    int e = i * 256 + t;
    int sc = e >> 6, cx = e & 63;
    xT[(size_t)(b * 1024 + s0 + sc) * 512 + c0 + cx] = tile[cx * 66 + sc];
  }
}

// ---- GEMM: Z[4608 x 4096] = W2[4608 x 512] * xT[chunk cols]^T ----------------
// 128x128 tile, BK=32, 4 waves (2x2), 16x16x32 bf16 MFMA, m97-style 2-barrier.
__global__ __launch_bounds__(256) void k_gemm(const u16* __restrict__ W2,
                                              const u16* __restrict__ xT,
                                              u16* __restrict__ Z, int b0) {
  __shared__ u16 At[128 * 32];
  __shared__ u16 Bt[128 * 32];
  const int t = threadIdx.x;
  const int m0 = blockIdx.y << 7;
  const int n0 = blockIdx.x << 7;
  const int l = t & 63;
  const int wy = ((t >> 7) & 1) << 6;
  const int wx = ((t >> 6) & 1) << 6;
  const int lrow = l & 15;
  const int lk8 = (l >> 4) << 3;

  const int srow = t >> 2;         // 0..63
  const int skc = (t & 3) << 3;    // 0,8,16,24
  const u16* gA = W2 + (size_t)(m0 + srow) * 512 + skc;
  const u16* gB = xT + (size_t)(b0 * 1024 + n0 + srow) * 512 + skc;
  u16* lA = At + srow * 32 + skc;
  u16* lB = Bt + srow * 32 + skc;

  f32x4 acc[4][4] = {};

  for (int k0 = 0; k0 < 512; k0 += 32) {
    u16x8 va0 = *(const u16x8*)(gA + k0);
    u16x8 va1 = *(const u16x8*)(gA + k0 + 64 * 512);
    u16x8 vb0 = *(const u16x8*)(gB + k0);
    u16x8 vb1 = *(const u16x8*)(gB + k0 + 64 * 512);
    *(u16x8*)lA = va0;
    *(u16x8*)(lA + 64 * 32) = va1;
    *(u16x8*)lB = vb0;
    *(u16x8*)(lB + 64 * 32) = vb1;
    __syncthreads();
    bf16x8 av[4], bv[4];
#pragma unroll
    for (int i = 0; i < 4; ++i)
      av[i] = *(const bf16x8*)(At + (wy + i * 16 + lrow) * 32 + lk8);
#pragma unroll
    for (int j = 0; j < 4; ++j)
      bv[j] = *(const bf16x8*)(Bt + (wx + j * 16 + lrow) * 32 + lk8);
#pragma unroll
    for (int i = 0; i < 4; ++i)
#pragma unroll
      for (int j = 0; j < 4; ++j)
        acc[i][j] = __builtin_amdgcn_mfma_f32_16x16x32_bf16(av[i], bv[j], acc[i][j], 0, 0, 0);
    __syncthreads();
  }

  const int mr = m0 + wy + ((l >> 4) << 2);  // C/D: row=(lane>>4)*4+reg
  const int nc = n0 + wx + lrow;             //      col=lane&15
#pragma unroll
  for (int i = 0; i < 4; ++i)
#pragma unroll
    for (int j = 0; j < 4; ++j)
#pragma unroll
      for (int r = 0; r < 4; ++r)
        Z[(size_t)(mr + i * 16 + r) * 4096 + nc + j * 16] = f2bf(acc[i][j][r]);
}

// ---- scatter Z -> y65 (LDS) -> FIR -> dcoef,noise,bias,lrelu,clamp -----------
__global__ __launch_bounds__(256) void k_scatter(
    const u16* __restrict__ Z, const float* __restrict__ dcoef,
    const float* __restrict__ noise, const float* __restrict__ nstr,
    const float* __restrict__ bias, float* __restrict__ out, int b0) {
  __shared__ float ybuf[67 * 68];  // y65 with +1 zero border each side, pad 68
  const int o = blockIdx.x;
  const int bb = blockIdx.y;
  const int b = b0 + bb;
  const int t = threadIdx.x;
  for (int i = t; i < 67 * 68; i += 256) ybuf[i] = 0.f;
  __syncthreads();
  const u16* Zp = Z + (size_t)o * 9 * 4096 + (size_t)bb * 1024;
  for (int idx = t; idx < 65 * 65; idx += 256) {
    int p = idx / 65;
    int q = idx - p * 65;
    int ph = p >> 1, qh = q >> 1;
    int ky0 = p & 1;
    int kx0 = q & 1;
    bool vy0 = ph < 32;
    bool vy1 = !(p & 1) && (ph >= 1);
    bool vx0 = qh < 32;
    bool vx1 = !(q & 1) && (qh >= 1);
    float s = 0.f;
    if (vy0 && vx0) s += bf2f(Zp[(ky0 * 3 + kx0) * 4096 + ph * 32 + qh]);
    if (vy0 && vx1) s += bf2f(Zp[(ky0 * 3 + 2) * 4096 + ph * 32 + qh - 1]);
    if (vy1 && vx0) s += bf2f(Zp[(6 + kx0) * 4096 + (ph - 1) * 32 + qh]);
    if (vy1 && vx1) s += bf2f(Zp[8 * 4096 + (ph - 1) * 32 + qh - 1]);
    ybuf[(p + 1) * 68 + q + 1] = s;
  }
  __syncthreads();
  const float dc = dcoef[b * 512 + o];
  const float ns = nstr[0];
  const float bo = bias[o];
#pragma unroll
  for (int r = 0; r < 16; ++r) {
    int idx = r * 256 + t;
    int m = idx >> 6, n = idx & 63;
    float acc = 0.f;
#pragma unroll
    for (int u = 0; u < 4; ++u) {
      const float* row = ybuf + (m + u) * 68 + n;
      float rs = row[0] + 3.f * row[1] + 3.f * row[2] + row[3];
      acc += (u == 1 || u == 2) ? 3.f * rs : rs;
    }
    acc *= 0.0625f;  // f2 = outer(1,3,3,1)/16
    float v = acc * dc + noise[(b << 12) + idx] * ns + bo;
    v = (v > 0.f ? v : 0.2f * v) * 1.4142135623730951f;
    v = fminf(fmaxf(v, -256.f), 256.f);
    out[((size_t)(b * 512 + o) << 12) + idx] = v;
  }
}

extern "C" void kernel_launch(void* const* d_in, const int* in_sizes, int n_in,
                              void* d_out, int out_size, void* d_ws, size_t ws_size,
                              hipStream_t stream) {
  const float* x = (const float*)d_in[0];
  const float* wl = (const float*)d_in[1];
  const float* aw = (const float*)d_in[2];
  const float* ab = (const float*)d_in[3];
  const float* cw = (const float*)d_in[4];
  const float* noise = (const float*)d_in[5];
  const float* nstr = (const float*)d_in[6];
  const float* bias = (const float*)d_in[7];
  float* out = (float*)d_out;

  // ws layout (59.3 MB): style f32[8192] | dcoef f32[8192] | W2 bf16[4608*512]
  //                      | xT bf16[16*1024*512] | Z bf16[4608*4096]
  float* style = (float*)d_ws;
  float* dcoef = style + 8192;
  u16* W2 = (u16*)(dcoef + 8192);
  u16* xT = W2 + 4608 * 512;
  u16* Z = xT + 16 * 1024 * 512;

  k_style<<<dim3(2, 16), 256, 0, stream>>>(wl, aw, ab, style);
  k_dcoef<<<dim3(512), 256, 0, stream>>>(cw, style, dcoef);
  k_pack<<<dim3(9216), 256, 0, stream>>>(cw, W2);
  k_xt<<<dim3(16, 8, 16), 256, 0, stream>>>(x, style, xT);
  for (int b0 = 0; b0 < NB; b0 += CHUNK) {
    k_gemm<<<dim3(32, 36), 256, 0, stream>>>(W2, xT, Z, b0);
    k_scatter<<<dim3(512, CHUNK), 256, 0, stream>>>(Z, dcoef, noise, nstr, bias, out, b0);
  }
}

// Round 5
// 393.393 us; speedup vs baseline: 1.1877x; 1.1877x over previous
//
#include <hip/hip_runtime.h>
#include <hip/hip_bf16.h>

// SynthesisConv: style affine -> demod -> conv_transpose(up=2,k=3) -> FIR 4x4
// -> noise + bias + lrelu*sqrt(2) + clamp(+-256).  Inputs f32, output f32.
//
//   style folds into x (B-operand column scale), dcoef folds into epilogue.
//   Z[(o,ky,kx),(b,i,j)] = sum_c w[o,c,ky,kx] * x'[b,c,i,j]   (one shared GEMM)
//   y65[2i+ky, 2j+kx] += Z ; out = FIR(y65)*dcoef + noise*ns + bias -> lrelu -> clamp
// R5: R4 with k_pack division fixed (hand-rolled magic for /9 was wrong ->
//     negative LDS index -> garbage W2 -> rail clamp). Compiler magic now.

typedef unsigned short u16;
typedef unsigned int u32;
typedef u16 u16x8 __attribute__((ext_vector_type(8)));
typedef __bf16 bf16x8 __attribute__((ext_vector_type(8)));
typedef float f32x4 __attribute__((ext_vector_type(4)));

#define NB 16

__device__ __forceinline__ float bf2f(u16 v) {
  unsigned int u = ((unsigned int)v) << 16;
  float f;
  __builtin_memcpy(&f, &u, 4);
  return f;
}
__device__ __forceinline__ u16 f2bf(float f) {
  __hip_bfloat16 h = __float2bfloat16(f);  // RNE
  u16 r;
  __builtin_memcpy(&r, &h, 2);
  return r;
}
__device__ __forceinline__ void async16(u16* lds, const u16* g) {
  __builtin_amdgcn_global_load_lds(
      (const __attribute__((address_space(1))) u32*)g,
      (__attribute__((address_space(3))) u32*)lds, 16, 0, 0);
}

// ---- style[b,c] = sum_k wl[b,k]*aw[c,k]/sqrt(512) + ab[c] ---------------------
__global__ __launch_bounds__(256) void k_style(const float* __restrict__ wl,
                                               const float* __restrict__ aw,
                                               const float* __restrict__ ab,
                                               float* __restrict__ style) {
  __shared__ float lw[512];
  const int b = blockIdx.y;
  const int c = blockIdx.x * 256 + threadIdx.x;
  for (int k = threadIdx.x; k < 512; k += 256) lw[k] = wl[b * 512 + k];
  __syncthreads();
  const float* row = aw + (size_t)c * 512;
  float acc = 0.f;
#pragma unroll 8
  for (int k = 0; k < 512; ++k) acc += lw[k] * row[k];
  style[b * 512 + c] = acc * 0.04419417382415922f + ab[c];
}

// ---- dcoef[b,o] = rsqrt(sum_c style^2 * sum_k w[o,c,k]^2 + 1e-8) -------------
__global__ __launch_bounds__(256) void k_dcoef(const float* __restrict__ cw,
                                               const float* __restrict__ style,
                                               float* __restrict__ dcoef) {
  __shared__ float wsq[512];
  const int o = blockIdx.x, t = threadIdx.x;
  for (int c = t; c < 512; c += 256) {
    const float* p = cw + (size_t)o * 4608 + (size_t)c * 9;
    float s = 0.f;
#pragma unroll
    for (int k = 0; k < 9; ++k) {
      float v = p[k];
      s += v * v;
    }
    wsq[c] = s;
  }
  __syncthreads();
  const int w = t >> 6, l = t & 63;
  for (int b = w; b < NB; b += 4) {
    float part = 0.f;
#pragma unroll
    for (int c = l; c < 512; c += 64) {
      float st = style[b * 512 + c];
      part += st * st * wsq[c];
    }
#pragma unroll
    for (int off = 32; off; off >>= 1) part += __shfl_down(part, off, 64);
    if (l == 0) dcoef[b * 512 + o] = 1.0f / sqrtf(part + 1e-8f);
  }
}

// ---- pack W2[(o*9+kp)*512 + c] = bf16(cw[o*4608 + c*9 + kp]) -----------------
__global__ __launch_bounds__(256) void k_pack(const float* __restrict__ cw,
                                              u16* __restrict__ W2) {
  __shared__ u16 lw[4608];
  const int o = blockIdx.x, t = threadIdx.x;
  const float* src = cw + (size_t)o * 4608;
  for (int v = t; v < 4608; v += 256) {
    unsigned c = (unsigned)v / 9u;   // compiler emits correct magic
    unsigned kp = (unsigned)v % 9u;
    lw[kp * 512 + c] = f2bf(src[v]);
  }
  __syncthreads();
  u16* dst = W2 + (size_t)o * 4608;
  for (int v = t; v < 576; v += 256)
    *(u16x8*)(dst + v * 8) = *(const u16x8*)(lw + v * 8);
}

// ---- xT[b,s,c] = bf16(x[b,c,s] * style[b,c])  (LDS 64x64 transpose) ----------
__global__ __launch_bounds__(256) void k_xt(const float* __restrict__ x,
                                            const float* __restrict__ style,
                                            u16* __restrict__ xT) {
  __shared__ u16 tile[64 * 66];
  const int b = blockIdx.z, c0 = blockIdx.y << 6, s0 = blockIdx.x << 6;
  const int t = threadIdx.x;
#pragma unroll
  for (int i = 0; i < 16; ++i) {
    int e = i * 256 + t;
    int cc = e >> 6, ss = e & 63;
    int c = c0 + cc;
    float v = x[(size_t)(b * 512 + c) * 1024 + s0 + ss] * style[b * 512 + c];
    tile[cc * 66 + ss] = f2bf(v);
  }
  __syncthreads();
#pragma unroll
  for (int i = 0; i < 16; ++i) {
    int e = i * 256 + t;
    int sc = e >> 6, cx = e & 63;
    xT[(size_t)(b * 1024 + s0 + sc) * 512 + c0 + cx] = tile[cx * 66 + sc];
  }
}

// ---- GEMM: Z[4608 x 16384] = W2[4608 x 512] * xT[16384 x 512]^T --------------
// 128x128 tile, BK=32, 4 waves (2x2), 16x16x32 bf16 MFMA, async LDS staging.
__global__ __launch_bounds__(256) void k_gemm(const u16* __restrict__ W2,
                                              const u16* __restrict__ xT,
                                              u16* __restrict__ Z) {
  __shared__ u16 At[128 * 32];
  __shared__ u16 Bt[128 * 32];
  const int t = threadIdx.x;
  const int m0 = blockIdx.y << 7;
  const int n0 = blockIdx.x << 7;
  const int l = t & 63;
  const int w = t >> 6;
  const int wy = ((t >> 7) & 1) << 6;
  const int wx = ((t >> 6) & 1) << 6;
  const int lrow = l & 15;
  const int lk8 = (l >> 4) << 3;

  // staging: srow=t>>2, skc=(t&3)*8 -> LDS byte addr 16*t = wave_base + lane*16
  const u16* gA = W2 + (size_t)(m0 + (t >> 2)) * 512 + ((t & 3) << 3);
  const u16* gB = xT + (size_t)(n0 + (t >> 2)) * 512 + ((t & 3) << 3);
  u16* lA0 = At + (w << 9);          // rows 0..63
  u16* lA1 = At + 2048 + (w << 9);   // rows 64..127
  u16* lB0 = Bt + (w << 9);
  u16* lB1 = Bt + 2048 + (w << 9);

  f32x4 acc[4][4] = {};

  for (int k0 = 0; k0 < 512; k0 += 32) {
    async16(lA0, gA + k0);
    async16(lA1, gA + k0 + 64 * 512);
    async16(lB0, gB + k0);
    async16(lB1, gB + k0 + 64 * 512);
    asm volatile("s_waitcnt vmcnt(0)" ::: "memory");
    __syncthreads();
    bf16x8 av[4], bv[4];
#pragma unroll
    for (int i = 0; i < 4; ++i)
      av[i] = *(const bf16x8*)(At + (wy + i * 16 + lrow) * 32 + lk8);
#pragma unroll
    for (int j = 0; j < 4; ++j)
      bv[j] = *(const bf16x8*)(Bt + (wx + j * 16 + lrow) * 32 + lk8);
#pragma unroll
    for (int i = 0; i < 4; ++i)
#pragma unroll
      for (int j = 0; j < 4; ++j)
        acc[i][j] = __builtin_amdgcn_mfma_f32_16x16x32_bf16(av[i], bv[j], acc[i][j], 0, 0, 0);
    __syncthreads();
  }

  const int mr = m0 + wy + ((l >> 4) << 2);  // C/D: row=(lane>>4)*4+reg
  const int nc = n0 + wx + lrow;             //      col=lane&15
#pragma unroll
  for (int i = 0; i < 4; ++i)
#pragma unroll
    for (int j = 0; j < 4; ++j)
#pragma unroll
      for (int r = 0; r < 4; ++r)
        Z[(size_t)(mr + i * 16 + r) * 16384 + nc + j * 16] = f2bf(acc[i][j][r]);
}

// ---- scatter Z -> y65 (LDS) -> FIR -> dcoef,noise,bias,lrelu,clamp -----------
__global__ __launch_bounds__(256) void k_scatter(
    const u16* __restrict__ Z, const float* __restrict__ dcoef,
    const float* __restrict__ noise, const float* __restrict__ nstr,
    const float* __restrict__ bias, float* __restrict__ out) {
  __shared__ u16 Zl[9 * 1024];     // 9 planes x 32x32, 18 KB
  __shared__ float ybuf[67 * 68];  // y65 with +1 zero border, pad 68
  const int o = blockIdx.x;
  const int b = blockIdx.y;
  const int t = threadIdx.x;
  // coalesced stage of the 9-plane slab
  const u16* Zp = Z + (size_t)o * 9 * 16384 + (size_t)b * 1024;
  for (int v = t; v < 1152; v += 256) {
    int kp = v >> 7, off = (v & 127) << 3;
    *(u16x8*)(Zl + kp * 1024 + off) = *(const u16x8*)(Zp + (size_t)kp * 16384 + off);
  }
  for (int i = t; i < 67 * 68; i += 256) ybuf[i] = 0.f;
  __syncthreads();
  for (int idx = t; idx < 65 * 65; idx += 256) {
    int p = idx / 65;
    int q = idx - p * 65;
    int ph = p >> 1, qh = q >> 1;
    int ky0 = p & 1;
    int kx0 = q & 1;
    bool vy0 = ph < 32;
    bool vy1 = !(p & 1) && (ph >= 1);
    bool vx0 = qh < 32;
    bool vx1 = !(q & 1) && (qh >= 1);
    float s = 0.f;
    if (vy0 && vx0) s += bf2f(Zl[(ky0 * 3 + kx0) * 1024 + ph * 32 + qh]);
    if (vy0 && vx1) s += bf2f(Zl[(ky0 * 3 + 2) * 1024 + ph * 32 + qh - 1]);
    if (vy1 && vx0) s += bf2f(Zl[(6 + kx0) * 1024 + (ph - 1) * 32 + qh]);
    if (vy1 && vx1) s += bf2f(Zl[8 * 1024 + (ph - 1) * 32 + qh - 1]);
    ybuf[(p + 1) * 68 + q + 1] = s;
  }
  __syncthreads();
  const float dc = dcoef[b * 512 + o];
  const float ns = nstr[0];
  const float bo = bias[o];
#pragma unroll
  for (int r = 0; r < 16; ++r) {
    int idx = r * 256 + t;
    int m = idx >> 6, n = idx & 63;
    float acc = 0.f;
#pragma unroll
    for (int u = 0; u < 4; ++u) {
      const float* row = ybuf + (m + u) * 68 + n;
      float rs = row[0] + 3.f * row[1] + 3.f * row[2] + row[3];
      acc += (u == 1 || u == 2) ? 3.f * rs : rs;
    }
    acc *= 0.0625f;  // f2 = outer(1,3,3,1)/16
    float v = acc * dc + noise[(b << 12) + idx] * ns + bo;
    v = (v > 0.f ? v : 0.2f * v) * 1.4142135623730951f;
    v = fminf(fmaxf(v, -256.f), 256.f);
    out[((size_t)(b * 512 + o) << 12) + idx] = v;
  }
}

extern "C" void kernel_launch(void* const* d_in, const int* in_sizes, int n_in,
                              void* d_out, int out_size, void* d_ws, size_t ws_size,
                              hipStream_t stream) {
  const float* x = (const float*)d_in[0];
  const float* wl = (const float*)d_in[1];
  const float* aw = (const float*)d_in[2];
  const float* ab = (const float*)d_in[3];
  const float* cw = (const float*)d_in[4];
  const float* noise = (const float*)d_in[5];
  const float* nstr = (const float*)d_in[6];
  const float* bias = (const float*)d_in[7];
  float* out = (float*)d_out;

  // ws layout (~165 MiB of 512): style f32[8192] | dcoef f32[8192]
  //   | W2 bf16[4608*512] | xT bf16[16384*512] | Z bf16[4608*16384]
  float* style = (float*)d_ws;
  float* dcoef = style + 8192;
  u16* W2 = (u16*)(dcoef + 8192);
  u16* xT = W2 + 4608 * 512;
  u16* Z = xT + (size_t)16384 * 512;

  k_style<<<dim3(2, 16), 256, 0, stream>>>(wl, aw, ab, style);
  k_dcoef<<<dim3(512), 256, 0, stream>>>(cw, style, dcoef);
  k_pack<<<dim3(512), 256, 0, stream>>>(cw, W2);
  k_xt<<<dim3(16, 8, 16), 256, 0, stream>>>(x, style, xT);
  k_gemm<<<dim3(128, 36), 256, 0, stream>>>(W2, xT, Z);
  k_scatter<<<dim3(512, 16), 256, 0, stream>>>(Z, dcoef, noise, nstr, bias, out);
}

// Round 6
// 383.615 us; speedup vs baseline: 1.2180x; 1.0255x over previous
//
#include <hip/hip_runtime.h>
#include <hip/hip_bf16.h>

// SynthesisConv: style affine -> demod -> conv_transpose(up=2,k=3) -> FIR 4x4
// -> noise + bias + lrelu*sqrt(2) + clamp(+-256).  Inputs f32, output f32.
//
//   style folds into x (B-operand column scale), dcoef folds into epilogue.
//   Z[(o,ky,kx),(b,i,j)] = sum_c w[o,c,ky,kx] * x'[b,c,i,j]   (one shared GEMM)
// R6: k_scatter rewritten as exact polyphase separable FIR (no y65 buffer,
//     no /65, ~10x less LDS traffic, swizzled H storage = conflict-free).

typedef unsigned short u16;
typedef unsigned int u32;
typedef u16 u16x8 __attribute__((ext_vector_type(8)));
typedef __bf16 bf16x8 __attribute__((ext_vector_type(8)));
typedef float f32x4 __attribute__((ext_vector_type(4)));

#define NB 16

__device__ __forceinline__ float bf2f(u16 v) {
  unsigned int u = ((unsigned int)v) << 16;
  float f;
  __builtin_memcpy(&f, &u, 4);
  return f;
}
__device__ __forceinline__ u16 f2bf(float f) {
  __hip_bfloat16 h = __float2bfloat16(f);  // RNE
  u16 r;
  __builtin_memcpy(&r, &h, 2);
  return r;
}
__device__ __forceinline__ void async16(u16* lds, const u16* g) {
  __builtin_amdgcn_global_load_lds(
      (const __attribute__((address_space(1))) u32*)g,
      (__attribute__((address_space(3))) u32*)lds, 16, 0, 0);
}

// ---- style[b,c] = sum_k wl[b,k]*aw[c,k]/sqrt(512) + ab[c] ---------------------
__global__ __launch_bounds__(256) void k_style(const float* __restrict__ wl,
                                               const float* __restrict__ aw,
                                               const float* __restrict__ ab,
                                               float* __restrict__ style) {
  __shared__ float lw[512];
  const int b = blockIdx.y;
  const int c = blockIdx.x * 256 + threadIdx.x;
  for (int k = threadIdx.x; k < 512; k += 256) lw[k] = wl[b * 512 + k];
  __syncthreads();
  const float* row = aw + (size_t)c * 512;
  float acc = 0.f;
#pragma unroll 8
  for (int k = 0; k < 512; ++k) acc += lw[k] * row[k];
  style[b * 512 + c] = acc * 0.04419417382415922f + ab[c];
}

// ---- dcoef[b,o] = rsqrt(sum_c style^2 * sum_k w[o,c,k]^2 + 1e-8) -------------
__global__ __launch_bounds__(256) void k_dcoef(const float* __restrict__ cw,
                                               const float* __restrict__ style,
                                               float* __restrict__ dcoef) {
  __shared__ float wsq[512];
  const int o = blockIdx.x, t = threadIdx.x;
  for (int c = t; c < 512; c += 256) {
    const float* p = cw + (size_t)o * 4608 + (size_t)c * 9;
    float s = 0.f;
#pragma unroll
    for (int k = 0; k < 9; ++k) {
      float v = p[k];
      s += v * v;
    }
    wsq[c] = s;
  }
  __syncthreads();
  const int w = t >> 6, l = t & 63;
  for (int b = w; b < NB; b += 4) {
    float part = 0.f;
#pragma unroll
    for (int c = l; c < 512; c += 64) {
      float st = style[b * 512 + c];
      part += st * st * wsq[c];
    }
#pragma unroll
    for (int off = 32; off; off >>= 1) part += __shfl_down(part, off, 64);
    if (l == 0) dcoef[b * 512 + o] = 1.0f / sqrtf(part + 1e-8f);
  }
}

// ---- pack W2[(o*9+kp)*512 + c] = bf16(cw[o*4608 + c*9 + kp]) -----------------
__global__ __launch_bounds__(256) void k_pack(const float* __restrict__ cw,
                                              u16* __restrict__ W2) {
  __shared__ u16 lw[4608];
  const int o = blockIdx.x, t = threadIdx.x;
  const float* src = cw + (size_t)o * 4608;
  for (int v = t; v < 4608; v += 256) {
    unsigned c = (unsigned)v / 9u;
    unsigned kp = (unsigned)v % 9u;
    lw[kp * 512 + c] = f2bf(src[v]);
  }
  __syncthreads();
  u16* dst = W2 + (size_t)o * 4608;
  for (int v = t; v < 576; v += 256)
    *(u16x8*)(dst + v * 8) = *(const u16x8*)(lw + v * 8);
}

// ---- xT[b,s,c] = bf16(x[b,c,s] * style[b,c])  (LDS 64x64 transpose) ----------
__global__ __launch_bounds__(256) void k_xt(const float* __restrict__ x,
                                            const float* __restrict__ style,
                                            u16* __restrict__ xT) {
  __shared__ u16 tile[64 * 66];
  const int b = blockIdx.z, c0 = blockIdx.y << 6, s0 = blockIdx.x << 6;
  const int t = threadIdx.x;
#pragma unroll
  for (int i = 0; i < 16; ++i) {
    int e = i * 256 + t;
    int cc = e >> 6, ss = e & 63;
    int c = c0 + cc;
    float v = x[(size_t)(b * 512 + c) * 1024 + s0 + ss] * style[b * 512 + c];
    tile[cc * 66 + ss] = f2bf(v);
  }
  __syncthreads();
#pragma unroll
  for (int i = 0; i < 16; ++i) {
    int e = i * 256 + t;
    int sc = e >> 6, cx = e & 63;
    xT[(size_t)(b * 1024 + s0 + sc) * 512 + c0 + cx] = tile[cx * 66 + sc];
  }
}

// ---- GEMM: Z[4608 x 16384] = W2[4608 x 512] * xT[16384 x 512]^T --------------
// 128x128 tile, BK=32, 4 waves (2x2), 16x16x32 bf16 MFMA, async LDS staging.
__global__ __launch_bounds__(256) void k_gemm(const u16* __restrict__ W2,
                                              const u16* __restrict__ xT,
                                              u16* __restrict__ Z) {
  __shared__ u16 At[128 * 32];
  __shared__ u16 Bt[128 * 32];
  const int t = threadIdx.x;
  const int m0 = blockIdx.y << 7;
  const int n0 = blockIdx.x << 7;
  const int l = t & 63;
  const int w = t >> 6;
  const int wy = ((t >> 7) & 1) << 6;
  const int wx = ((t >> 6) & 1) << 6;
  const int lrow = l & 15;
  const int lk8 = (l >> 4) << 3;

  const u16* gA = W2 + (size_t)(m0 + (t >> 2)) * 512 + ((t & 3) << 3);
  const u16* gB = xT + (size_t)(n0 + (t >> 2)) * 512 + ((t & 3) << 3);
  u16* lA0 = At + (w << 9);
  u16* lA1 = At + 2048 + (w << 9);
  u16* lB0 = Bt + (w << 9);
  u16* lB1 = Bt + 2048 + (w << 9);

  f32x4 acc[4][4] = {};

  for (int k0 = 0; k0 < 512; k0 += 32) {
    async16(lA0, gA + k0);
    async16(lA1, gA + k0 + 64 * 512);
    async16(lB0, gB + k0);
    async16(lB1, gB + k0 + 64 * 512);
    asm volatile("s_waitcnt vmcnt(0)" ::: "memory");
    __syncthreads();
    bf16x8 av[4], bv[4];
#pragma unroll
    for (int i = 0; i < 4; ++i)
      av[i] = *(const bf16x8*)(At + (wy + i * 16 + lrow) * 32 + lk8);
#pragma unroll
    for (int j = 0; j < 4; ++j)
      bv[j] = *(const bf16x8*)(Bt + (wx + j * 16 + lrow) * 32 + lk8);
#pragma unroll
    for (int i = 0; i < 4; ++i)
#pragma unroll
      for (int j = 0; j < 4; ++j)
        acc[i][j] = __builtin_amdgcn_mfma_f32_16x16x32_bf16(av[i], bv[j], acc[i][j], 0, 0, 0);
    __syncthreads();
  }

  const int mr = m0 + wy + ((l >> 4) << 2);
  const int nc = n0 + wx + lrow;
#pragma unroll
  for (int i = 0; i < 4; ++i)
#pragma unroll
    for (int j = 0; j < 4; ++j)
#pragma unroll
      for (int r = 0; r < 4; ++r)
        Z[(size_t)(mr + i * 16 + r) * 16384 + nc + j * 16] = f2bf(acc[i][j][r]);
}

// ---- scatter v2: polyphase separable FIR, no y65 materialization -------------
// H_ky[i][n] = horiz FIR of upsampled plane-row i of ky-group; stored swizzled:
//   he (n=2j) at [i*64+j], ho (n=2j+1) at [i*64+32+j]  -> conflict-free.
// out[2i]   = H1[i-1] + 3(H0[i]+H2[i-1]) + 3 H1[i] + (H0[i+1]+H2[i])
// out[2i+1] = (H0[i]+H2[i-1]) + 3 H1[i] + 3(H0[i+1]+H2[i]) + H1[i+1]
__global__ __launch_bounds__(256) void k_scatter(
    const u16* __restrict__ Z, const float* __restrict__ dcoef,
    const float* __restrict__ noise, const float* __restrict__ nstr,
    const float* __restrict__ bias, float* __restrict__ out) {
  __shared__ u16 Zl[9 * 1024];       // 9 planes x 32x32, 18 KB
  __shared__ float Hl[3 * 2048];     // H[ky][32 rows][64 swizzled], 24 KB
  const int o = blockIdx.x;
  const int b = blockIdx.y;
  const int t = threadIdx.x;
  const u16* Zp = Z + (size_t)o * 9 * 16384 + (size_t)b * 1024;
  for (int v = t; v < 1152; v += 256) {
    int kp = v >> 7, off = (v & 127) << 3;
    *(u16x8*)(Zl + kp * 1024 + off) = *(const u16x8*)(Zp + (size_t)kp * 16384 + off);
  }
  __syncthreads();
  // horizontal polyphase FIR: 3072 (ky,i,j) cells, each -> (he,ho)
#pragma unroll
  for (int e = 0; e < 12; ++e) {
    int idx = e * 256 + t;  // 0..3071
    int ky = idx >> 10;
    int i = (idx >> 5) & 31;
    int j = idx & 31;
    const u16* P0 = Zl + (ky * 3 + 0) * 1024 + i * 32;
    const u16* P1 = P0 + 1024;
    const u16* P2 = P0 + 2048;
    float Ej = bf2f(P0[j]) + (j >= 1 ? bf2f(P2[j - 1]) : 0.f);
    float Ej1 = (j < 31 ? bf2f(P0[j + 1]) : 0.f) + bf2f(P2[j]);
    float Ojm = j >= 1 ? bf2f(P1[j - 1]) : 0.f;
    float Oj = bf2f(P1[j]);
    float Ojp = j < 31 ? bf2f(P1[j + 1]) : 0.f;
    float* hp = Hl + ky * 2048 + i * 64 + j;
    hp[0] = Ojm + 3.f * Ej + 3.f * Oj + Ej1;        // he -> [j]
    hp[32] = Ej + 3.f * Oj + 3.f * Ej1 + Ojp;       // ho -> [32+j]
  }
  __syncthreads();
  // vertical FIR + epilogue: thread = (column n, quarter of rows)
  const float dc = dcoef[b * 512 + o] * 0.0625f;
  const float ns = nstr[0];
  const float bo = bias[o];
  const int n = t & 63;
  const int i0 = (t >> 6) << 3;  // 0,8,16,24
  const int sw = ((n & 1) << 5) | (n >> 1);  // swizzled column index
  const float* H0 = Hl + sw;
  const float* H1 = Hl + 2048 + sw;
  const float* H2 = Hl + 4096 + sw;
  float h0 = H0[i0 * 64];
  float h1 = H1[i0 * 64];
  float h1p = (i0 > 0) ? H1[(i0 - 1) * 64] : 0.f;
  float h2p = (i0 > 0) ? H2[(i0 - 1) * 64] : 0.f;
  const float* nz = noise + ((size_t)b << 12) + n;
  float* op = out + (((size_t)(b * 512 + o)) << 12) + n;
#pragma unroll
  for (int s = 0; s < 8; ++s) {
    int i = i0 + s;
    float h0n = (i < 31) ? H0[(i + 1) * 64] : 0.f;
    float h1n = (i < 31) ? H1[(i + 1) * 64] : 0.f;
    float h2 = H2[i * 64];
    float ev = h1p + 3.f * (h0 + h2p) + 3.f * h1 + (h0n + h2);
    float od = (h0 + h2p) + 3.f * h1 + 3.f * (h0n + h2) + h1n;
    int m = 2 * i;
    float v0 = ev * dc + nz[(size_t)m * 64] * ns + bo;
    v0 = (v0 > 0.f ? v0 : 0.2f * v0) * 1.4142135623730951f;
    v0 = fminf(fmaxf(v0, -256.f), 256.f);
    op[(size_t)m * 64] = v0;
    float v1 = od * dc + nz[(size_t)(m + 1) * 64] * ns + bo;
    v1 = (v1 > 0.f ? v1 : 0.2f * v1) * 1.4142135623730951f;
    v1 = fminf(fmaxf(v1, -256.f), 256.f);
    op[(size_t)(m + 1) * 64] = v1;
    h0 = h0n;
    h1p = h1;
    h1 = h1n;
    h2p = h2;
  }
}

extern "C" void kernel_launch(void* const* d_in, const int* in_sizes, int n_in,
                              void* d_out, int out_size, void* d_ws, size_t ws_size,
                              hipStream_t stream) {
  const float* x = (const float*)d_in[0];
  const float* wl = (const float*)d_in[1];
  const float* aw = (const float*)d_in[2];
  const float* ab = (const float*)d_in[3];
  const float* cw = (const float*)d_in[4];
  const float* noise = (const float*)d_in[5];
  const float* nstr = (const float*)d_in[6];
  const float* bias = (const float*)d_in[7];
  float* out = (float*)d_out;

  float* style = (float*)d_ws;
  float* dcoef = style + 8192;
  u16* W2 = (u16*)(dcoef + 8192);
  u16* xT = W2 + 4608 * 512;
  u16* Z = xT + (size_t)16384 * 512;

  k_style<<<dim3(2, 16), 256, 0, stream>>>(wl, aw, ab, style);
  k_dcoef<<<dim3(512), 256, 0, stream>>>(cw, style, dcoef);
  k_pack<<<dim3(512), 256, 0, stream>>>(cw, W2);
  k_xt<<<dim3(16, 8, 16), 256, 0, stream>>>(x, style, xT);
  k_gemm<<<dim3(128, 36), 256, 0, stream>>>(W2, xT, Z);
  k_scatter<<<dim3(512, 16), 256, 0, stream>>>(Z, dcoef, noise, nstr, bias, out);
}

// Round 7
// 379.635 us; speedup vs baseline: 1.2307x; 1.0105x over previous
//
#include <hip/hip_runtime.h>
#include <hip/hip_bf16.h>

// SynthesisConv: style affine -> demod -> conv_transpose(up=2,k=3) -> FIR 4x4
// -> noise + bias + lrelu*sqrt(2) + clamp(+-256).  Inputs f32, output f32.
//
//   style folds into x (B-operand column scale), dcoef folds into epilogue.
//   Z[(o,ky,kx),(b,i,j)] = sum_c w[o,c,ky,kx] * x'[b,c,i,j]   (one shared GEMM)
// R7: k_gemm LDS chunk-swizzle kills the 8-way ds_read_b128 bank conflict
//     (slot s holds k-chunk (s+(r>>1))&3; read slot = (c0-(R>>1))&3, which
//     folds to a per-lane constant sK). dcoef+pack merged (one cw read).

typedef unsigned short u16;
typedef unsigned int u32;
typedef u16 u16x8 __attribute__((ext_vector_type(8)));
typedef __bf16 bf16x8 __attribute__((ext_vector_type(8)));
typedef float f32x4 __attribute__((ext_vector_type(4)));

#define NB 16

__device__ __forceinline__ float bf2f(u16 v) {
  unsigned int u = ((unsigned int)v) << 16;
  float f;
  __builtin_memcpy(&f, &u, 4);
  return f;
}
__device__ __forceinline__ u16 f2bf(float f) {
  __hip_bfloat16 h = __float2bfloat16(f);  // RNE
  u16 r;
  __builtin_memcpy(&r, &h, 2);
  return r;
}
__device__ __forceinline__ void async16(u16* lds, const u16* g) {
  __builtin_amdgcn_global_load_lds(
      (const __attribute__((address_space(1))) u32*)g,
      (__attribute__((address_space(3))) u32*)lds, 16, 0, 0);
}

// ---- style[b,c] = sum_k wl[b,k]*aw[c,k]/sqrt(512) + ab[c] ---------------------
__global__ __launch_bounds__(256) void k_style(const float* __restrict__ wl,
                                               const float* __restrict__ aw,
                                               const float* __restrict__ ab,
                                               float* __restrict__ style) {
  __shared__ float lw[512];
  const int b = blockIdx.y;
  const int c = blockIdx.x * 256 + threadIdx.x;
  for (int k = threadIdx.x; k < 512; k += 256) lw[k] = wl[b * 512 + k];
  __syncthreads();
  const float* row = aw + (size_t)c * 512;
  float acc = 0.f;
#pragma unroll 8
  for (int k = 0; k < 512; ++k) acc += lw[k] * row[k];
  style[b * 512 + c] = acc * 0.04419417382415922f + ab[c];
}

// ---- merged: W2 pack (bf16, [o*9+kp][c]) + dcoef[b,o] ------------------------
__global__ __launch_bounds__(256) void k_wprep(const float* __restrict__ cw,
                                               const float* __restrict__ style,
                                               float* __restrict__ dcoef,
                                               u16* __restrict__ W2) {
  __shared__ u16 lw[4608];
  __shared__ float wsq[512];
  const int o = blockIdx.x, t = threadIdx.x;
  const float* src = cw + (size_t)o * 4608;
  for (int v = t; v < 4608; v += 256) {
    unsigned c = (unsigned)v / 9u;
    unsigned kp = (unsigned)v % 9u;
    lw[kp * 512 + c] = f2bf(src[v]);
  }
  for (int c = t; c < 512; c += 256) {
    const float* p = src + (size_t)c * 9;
    float s = 0.f;
#pragma unroll
    for (int k = 0; k < 9; ++k) {
      float v = p[k];
      s += v * v;
    }
    wsq[c] = s;
  }
  __syncthreads();
  u16* dst = W2 + (size_t)o * 4608;
  for (int v = t; v < 576; v += 256)
    *(u16x8*)(dst + v * 8) = *(const u16x8*)(lw + v * 8);
  const int w = t >> 6, l = t & 63;
  for (int b = w; b < NB; b += 4) {
    float part = 0.f;
#pragma unroll
    for (int c = l; c < 512; c += 64) {
      float st = style[b * 512 + c];
      part += st * st * wsq[c];
    }
#pragma unroll
    for (int off = 32; off; off >>= 1) part += __shfl_down(part, off, 64);
    if (l == 0) dcoef[b * 512 + o] = 1.0f / sqrtf(part + 1e-8f);
  }
}

// ---- xT[b,s,c] = bf16(x[b,c,s] * style[b,c])  (LDS 64x64 transpose) ----------
__global__ __launch_bounds__(256) void k_xt(const float* __restrict__ x,
                                            const float* __restrict__ style,
                                            u16* __restrict__ xT) {
  __shared__ u16 tile[64 * 66];
  const int b = blockIdx.z, c0 = blockIdx.y << 6, s0 = blockIdx.x << 6;
  const int t = threadIdx.x;
#pragma unroll
  for (int i = 0; i < 16; ++i) {
    int e = i * 256 + t;
    int cc = e >> 6, ss = e & 63;
    int c = c0 + cc;
    float v = x[(size_t)(b * 512 + c) * 1024 + s0 + ss] * style[b * 512 + c];
    tile[cc * 66 + ss] = f2bf(v);
  }
  __syncthreads();
#pragma unroll
  for (int e = 0; e < 2; ++e) {
    int idx = e * 256 + t;          // 512 = 64 rows x 8 col-groups
    int sc = idx >> 3;
    int cg = (idx & 7) << 3;
    u16x8 v;
#pragma unroll
    for (int g = 0; g < 8; ++g) v[g] = tile[(cg + g) * 66 + sc];
    *(u16x8*)(xT + (size_t)(b * 1024 + s0 + sc) * 512 + c0 + cg) = v;
  }
}

// ---- GEMM: Z[4608 x 16384] = W2[4608 x 512] * xT[16384 x 512]^T --------------
// 128x128 tile, BK=32, 4 waves (2x2), 16x16x32 bf16 MFMA, async LDS staging.
// Chunk swizzle: LDS slot (row r, s) holds k-chunk (s+(r>>1))&3 -> 2-way banks.
__global__ __launch_bounds__(256) void k_gemm(const u16* __restrict__ W2,
                                              const u16* __restrict__ xT,
                                              u16* __restrict__ Z) {
  __shared__ u16 At[128 * 32];
  __shared__ u16 Bt[128 * 32];
  const int t = threadIdx.x;
  const int m0 = blockIdx.y << 7;
  const int n0 = blockIdx.x << 7;
  const int l = t & 63;
  const int w = t >> 6;
  const int wy = ((t >> 7) & 1) << 6;
  const int wx = ((t >> 6) & 1) << 6;
  const int lrow = l & 15;

  // staging with chunk swizzle: lane t covers (row r=t>>2, slot s=t&3),
  // loads global k-chunk (s + (r>>1)) & 3
  const int sr = t >> 2;
  const int sch = ((t & 3) + (sr >> 1)) & 3;
  const u16* gA = W2 + (size_t)(m0 + sr) * 512 + (sch << 3);
  const u16* gB = xT + (size_t)(n0 + sr) * 512 + (sch << 3);
  u16* lA0 = At + (w << 9);
  u16* lA1 = At + 2048 + (w << 9);
  u16* lB0 = Bt + (w << 9);
  u16* lB1 = Bt + 2048 + (w << 9);

  // read-side swizzled chunk offset: sK = (c0 - (lrow>>1)) & 3, c0 = l>>4
  const int sk8 = (((l >> 4) - (lrow >> 1)) & 3) << 3;

  f32x4 acc[4][4] = {};

  for (int k0 = 0; k0 < 512; k0 += 32) {
    async16(lA0, gA + k0);
    async16(lA1, gA + k0 + 64 * 512);
    async16(lB0, gB + k0);
    async16(lB1, gB + k0 + 64 * 512);
    asm volatile("s_waitcnt vmcnt(0)" ::: "memory");
    __syncthreads();
    bf16x8 av[4], bv[4];
#pragma unroll
    for (int i = 0; i < 4; ++i)
      av[i] = *(const bf16x8*)(At + (wy + i * 16 + lrow) * 32 + sk8);
#pragma unroll
    for (int j = 0; j < 4; ++j)
      bv[j] = *(const bf16x8*)(Bt + (wx + j * 16 + lrow) * 32 + sk8);
#pragma unroll
    for (int i = 0; i < 4; ++i)
#pragma unroll
      for (int j = 0; j < 4; ++j)
        acc[i][j] = __builtin_amdgcn_mfma_f32_16x16x32_bf16(av[i], bv[j], acc[i][j], 0, 0, 0);
    __syncthreads();
  }

  const int mr = m0 + wy + ((l >> 4) << 2);
  const int nc = n0 + wx + lrow;
#pragma unroll
  for (int i = 0; i < 4; ++i)
#pragma unroll
    for (int j = 0; j < 4; ++j)
#pragma unroll
      for (int r = 0; r < 4; ++r)
        Z[(size_t)(mr + i * 16 + r) * 16384 + nc + j * 16] = f2bf(acc[i][j][r]);
}

// ---- scatter: polyphase separable FIR + epilogue -----------------------------
__global__ __launch_bounds__(256) void k_scatter(
    const u16* __restrict__ Z, const float* __restrict__ dcoef,
    const float* __restrict__ noise, const float* __restrict__ nstr,
    const float* __restrict__ bias, float* __restrict__ out) {
  __shared__ u16 Zl[9 * 1024];
  __shared__ float Hl[3 * 2048];
  const int o = blockIdx.x;
  const int b = blockIdx.y;
  const int t = threadIdx.x;
  const u16* Zp = Z + (size_t)o * 9 * 16384 + (size_t)b * 1024;
  for (int v = t; v < 1152; v += 256) {
    int kp = v >> 7, off = (v & 127) << 3;
    *(u16x8*)(Zl + kp * 1024 + off) = *(const u16x8*)(Zp + (size_t)kp * 16384 + off);
  }
  __syncthreads();
#pragma unroll
  for (int e = 0; e < 12; ++e) {
    int idx = e * 256 + t;
    int ky = idx >> 10;
    int i = (idx >> 5) & 31;
    int j = idx & 31;
    const u16* P0 = Zl + (ky * 3 + 0) * 1024 + i * 32;
    const u16* P1 = P0 + 1024;
    const u16* P2 = P0 + 2048;
    float Ej = bf2f(P0[j]) + (j >= 1 ? bf2f(P2[j - 1]) : 0.f);
    float Ej1 = (j < 31 ? bf2f(P0[j + 1]) : 0.f) + bf2f(P2[j]);
    float Ojm = j >= 1 ? bf2f(P1[j - 1]) : 0.f;
    float Oj = bf2f(P1[j]);
    float Ojp = j < 31 ? bf2f(P1[j + 1]) : 0.f;
    float* hp = Hl + ky * 2048 + i * 64 + j;
    hp[0] = Ojm + 3.f * Ej + 3.f * Oj + Ej1;
    hp[32] = Ej + 3.f * Oj + 3.f * Ej1 + Ojp;
  }
  __syncthreads();
  const float dc = dcoef[b * 512 + o] * 0.0625f;
  const float ns = nstr[0];
  const float bo = bias[o];
  const int n = t & 63;
  const int i0 = (t >> 6) << 3;
  const int sw = ((n & 1) << 5) | (n >> 1);
  const float* H0 = Hl + sw;
  const float* H1 = Hl + 2048 + sw;
  const float* H2 = Hl + 4096 + sw;
  float h0 = H0[i0 * 64];
  float h1 = H1[i0 * 64];
  float h1p = (i0 > 0) ? H1[(i0 - 1) * 64] : 0.f;
  float h2p = (i0 > 0) ? H2[(i0 - 1) * 64] : 0.f;
  const float* nz = noise + ((size_t)b << 12) + n;
  float* op = out + (((size_t)(b * 512 + o)) << 12) + n;
#pragma unroll
  for (int s = 0; s < 8; ++s) {
    int i = i0 + s;
    float h0n = (i < 31) ? H0[(i + 1) * 64] : 0.f;
    float h1n = (i < 31) ? H1[(i + 1) * 64] : 0.f;
    float h2 = H2[i * 64];
    float ev = h1p + 3.f * (h0 + h2p) + 3.f * h1 + (h0n + h2);
    float od = (h0 + h2p) + 3.f * h1 + 3.f * (h0n + h2) + h1n;
    int m = 2 * i;
    float v0 = ev * dc + nz[(size_t)m * 64] * ns + bo;
    v0 = (v0 > 0.f ? v0 : 0.2f * v0) * 1.4142135623730951f;
    v0 = fminf(fmaxf(v0, -256.f), 256.f);
    op[(size_t)m * 64] = v0;
    float v1 = od * dc + nz[(size_t)(m + 1) * 64] * ns + bo;
    v1 = (v1 > 0.f ? v1 : 0.2f * v1) * 1.4142135623730951f;
    v1 = fminf(fmaxf(v1, -256.f), 256.f);
    op[(size_t)(m + 1) * 64] = v1;
    h0 = h0n;
    h1p = h1;
    h1 = h1n;
    h2p = h2;
  }
}

extern "C" void kernel_launch(void* const* d_in, const int* in_sizes, int n_in,
                              void* d_out, int out_size, void* d_ws, size_t ws_size,
                              hipStream_t stream) {
  const float* x = (const float*)d_in[0];
  const float* wl = (const float*)d_in[1];
  const float* aw = (const float*)d_in[2];
  const float* ab = (const float*)d_in[3];
  const float* cw = (const float*)d_in[4];
  const float* noise = (const float*)d_in[5];
  const float* nstr = (const float*)d_in[6];
  const float* bias = (const float*)d_in[7];
  float* out = (float*)d_out;

  float* style = (float*)d_ws;
  float* dcoef = style + 8192;
  u16* W2 = (u16*)(dcoef + 8192);
  u16* xT = W2 + 4608 * 512;
  u16* Z = xT + (size_t)16384 * 512;

  k_style<<<dim3(2, 16), 256, 0, stream>>>(wl, aw, ab, style);
  k_wprep<<<dim3(512), 256, 0, stream>>>(cw, style, dcoef, W2);
  k_xt<<<dim3(16, 8, 16), 256, 0, stream>>>(x, style, xT);
  k_gemm<<<dim3(128, 36), 256, 0, stream>>>(W2, xT, Z);
  k_scatter<<<dim3(512, 16), 256, 0, stream>>>(Z, dcoef, noise, nstr, bias, out);
}